// Round 6
// baseline (330.138 us; speedup 1.0000x reference)
//
#include <hip/hip_runtime.h>
#include <hip/hip_bf16.h>
#include <cstdint>
#include <cstddef>

#define NH   16
#define DH   64
#define SQ   2048
#define NB   2
#define EM   1024
#define NREL 257
#define QSTR 258          // qrel row stride (elements)
#define SCL  0.18033688f  // 0.125 * log2(e)

typedef unsigned short ushort_t;
using bf16x8 = __attribute__((ext_vector_type(8))) __bf16;
using bf16x4 = __attribute__((ext_vector_type(4))) __bf16;
using f32x4  = __attribute__((ext_vector_type(4))) float;
#define MFMA16(a, b, c) __builtin_amdgcn_mfma_f32_16x16x32_bf16(a, b, c, 0, 0, 0)

__device__ __forceinline__ ushort_t f2bf(float f) {
    union { __bf16 h; ushort_t u; } x; x.h = (__bf16)f; return x.u;
}
__device__ __forceinline__ float bf2f(ushort_t u) {
    union { unsigned u; float f; } x; x.u = ((unsigned)u) << 16;
    return x.f;
}
__device__ __forceinline__ uint2 pack4(float a, float b, float c, float d) {
    union { bf16x4 v; uint2 u; } x;
    x.v = (bf16x4){ (__bf16)a, (__bf16)b, (__bf16)c, (__bf16)d };
    return x.u;
}
// kappa permutation within a 64-block: k = 16n + c16  ->  kap = 4*c16 + n
__device__ __forceinline__ int kperm(int x) {
    return (x & ~63) | ((x & 15) << 2) | ((x >> 4) & 3);
}
// LDS swizzle: row stride 128B, XOR 16B-slot by row&7 (G4 bank-conflict fix)
__device__ __forceinline__ int lswz(int row, int byteoff) {
    return row * 128 + (byteoff ^ ((row & 7) << 4));
}

// rvT[d][kperm(c)] = rv[c+1][d] bf16 (c in [0,256)); rkb zero-padded to 272 rows
__global__ __launch_bounds__(256)
void prep_tables(const float* __restrict__ rv, const float* __restrict__ rk,
                 ushort_t* __restrict__ rvT, ushort_t* __restrict__ rkb)
{
    int idx = blockIdx.x * 256 + threadIdx.x;
    if (idx < 64 * 256) {
        int d = idx >> 8, c = idx & 255;
        rvT[d * 256 + kperm(c)] = f2bf(rv[(size_t)(c + 1) * DH + d]);
    }
    idx -= 64 * 256;
    if (idx >= 0 && idx < 272 * 64) {
        int j = idx >> 6, d2 = idx & 63;
        rkb[idx] = (j < NREL) ? f2bf(rk[(size_t)j * DH + d2]) : (ushort_t)0;
    }
}

// ---------------------------------------------------------------------------
// bf16 NT GEMM with fused f32->bf16 staging: dst = A @ W^T + bias.
// A: f32 (ACVT=1) or bf16 (ACVT=0); W: always f32, converted while staging.
// 128x128 tile, BK=32, 4 waves. XCD-aware bijective swizzle (nwg % 8 == 0).
// MODE 0: f32 row-major; MODE 1: bf16 [B,H,S,D]; MODE 2: bf16 [B,H,D,S'] kappa.
// ---------------------------------------------------------------------------
template<int MODE, int ACVT>
__global__ __launch_bounds__(256)
void gemm_bt(const void* __restrict__ Av, const float* __restrict__ Wf,
             const float* __restrict__ bias, void* __restrict__ dstv,
             int M, int N, int K)
{
    __shared__ ushort_t As[128 * 40];
    __shared__ ushort_t Bs[128 * 40];
    const int t = threadIdx.x, lane = t & 63;
    const int wv = t >> 6, wr = wv >> 1, wc = wv & 1;
    const int g = lane >> 4, c16 = lane & 15;

    const int nwg = gridDim.x * gridDim.y;
    int flat = blockIdx.y * gridDim.x + blockIdx.x;
    int rm = (flat & 7) * (nwg >> 3) + (flat >> 3);
    const int n0 = (rm % gridDim.x) * 128;
    const int m0 = (rm / gridDim.x) * 128;

    f32x4 acc[4][4];
#pragma unroll
    for (int i = 0; i < 4; ++i)
#pragma unroll
        for (int j = 0; j < 4; ++j) acc[i][j] = (f32x4){0.f, 0.f, 0.f, 0.f};

    for (int k0 = 0; k0 < K; k0 += 32) {
        __syncthreads();
#pragma unroll
        for (int l = 0; l < 2; ++l) {
            const int fid = t + 256 * l;
            const int row = fid >> 2, ch = fid & 3;
            if (ACVT) {
                const float* Af = (const float*)Av;
                float4 a0 = *reinterpret_cast<const float4*>(Af + (size_t)(m0 + row) * K + k0 + ch * 8);
                float4 a1 = *reinterpret_cast<const float4*>(Af + (size_t)(m0 + row) * K + k0 + ch * 8 + 4);
                uint2 lo = pack4(a0.x, a0.y, a0.z, a0.w);
                uint2 hi = pack4(a1.x, a1.y, a1.z, a1.w);
                *reinterpret_cast<uint4*>(As + row * 40 + ch * 8) = make_uint4(lo.x, lo.y, hi.x, hi.y);
            } else {
                const ushort_t* Ab = (const ushort_t*)Av;
                *reinterpret_cast<uint4*>(As + row * 40 + ch * 8) =
                    *reinterpret_cast<const uint4*>(Ab + (size_t)(m0 + row) * K + k0 + ch * 8);
            }
            float4 w0 = *reinterpret_cast<const float4*>(Wf + (size_t)(n0 + row) * K + k0 + ch * 8);
            float4 w1_ = *reinterpret_cast<const float4*>(Wf + (size_t)(n0 + row) * K + k0 + ch * 8 + 4);
            uint2 lo = pack4(w0.x, w0.y, w0.z, w0.w);
            uint2 hi = pack4(w1_.x, w1_.y, w1_.z, w1_.w);
            *reinterpret_cast<uint4*>(Bs + row * 40 + ch * 8) = make_uint4(lo.x, lo.y, hi.x, hi.y);
        }
        __syncthreads();

        bf16x8 af[4], bfr[4];
#pragma unroll
        for (int i = 0; i < 4; ++i)
            af[i] = *reinterpret_cast<const bf16x8*>(As + (wr * 64 + i * 16 + c16) * 40 + g * 8);
#pragma unroll
        for (int j = 0; j < 4; ++j)
            bfr[j] = *reinterpret_cast<const bf16x8*>(Bs + (wc * 64 + j * 16 + c16) * 40 + g * 8);
#pragma unroll
        for (int i = 0; i < 4; ++i)
#pragma unroll
            for (int j = 0; j < 4; ++j)
                acc[i][j] = MFMA16(af[i], bfr[j], acc[i][j]);
    }

#pragma unroll
    for (int j = 0; j < 4; ++j) {
        const int n = n0 + wc * 64 + j * 16 + c16;
        const float bn = bias[n];
#pragma unroll
        for (int i = 0; i < 4; ++i) {
#pragma unroll
            for (int r = 0; r < 4; ++r) {
                const int m = m0 + wr * 64 + i * 16 + 4 * g + r;
                const float vv = acc[i][j][r] + bn;
                if (MODE == 0) {
                    ((float*)dstv)[(size_t)m * N + n] = vv;
                } else {
                    const int b = m >> 11, s = m & (SQ - 1);
                    const int h = n >> 6, dd = n & 63;
                    if (MODE == 1) {
                        ((ushort_t*)dstv)[(((size_t)b * NH + h) * SQ + s) * DH + dd] = f2bf(vv);
                    } else {
                        const int sp = kperm(s);
                        ((ushort_t*)dstv)[(((size_t)b * NH + h) * DH + dd) * SQ + sp] = f2bf(vv);
                    }
                }
            }
        }
    }
}

// ---------------------------------------------------------------------------
// qrel[r][j] = dot(qh[r], rk[j]) * SCL, bf16 out, stride QSTR.
// ---------------------------------------------------------------------------
__global__ __launch_bounds__(256)
void qrel_mfma(const ushort_t* __restrict__ qh, const ushort_t* __restrict__ rkb,
               ushort_t* __restrict__ qrel)
{
    const int t = threadIdx.x, lane = t & 63, w = t >> 6;
    const int g = lane >> 4, c16 = lane & 15;
    const size_t r0 = (size_t)blockIdx.x * 64 + w * 16;

    bf16x8 af[2];
#pragma unroll
    for (int ks = 0; ks < 2; ++ks)
        af[ks] = *reinterpret_cast<const bf16x8*>(qh + (r0 + c16) * DH + ks * 32 + g * 8);

    f32x4 acc[17];
#pragma unroll
    for (int n = 0; n < 17; ++n) acc[n] = (f32x4){0.f, 0.f, 0.f, 0.f};
#pragma unroll
    for (int n = 0; n < 17; ++n)
#pragma unroll
        for (int ks = 0; ks < 2; ++ks) {
            bf16x8 bf = *reinterpret_cast<const bf16x8*>(
                rkb + (size_t)(16 * n + c16) * DH + ks * 32 + g * 8);
            acc[n] = MFMA16(af[ks], bf, acc[n]);
        }
#pragma unroll
    for (int n = 0; n < 17; ++n) {
        const int j = 16 * n + c16;
        if (j < NREL) {
#pragma unroll
            for (int r = 0; r < 4; ++r)
                qrel[(r0 + 4 * g + r) * QSTR + j] = f2bf(acc[n][r] * SCL);
        }
    }
}

// ---------------------------------------------------------------------------
// Flash attention, QBLK=128 (4 waves x 2 strips of 16 rows), KVBLK=64.
// w1 = P@V (kappa-space), lac/b0/b256 stats; band P tiles (6 per q-block)
// stored coalesced to Ptile[G][6][128][64]. LDS XOR-swizzled (stride 128B).
// ---------------------------------------------------------------------------
__global__ __launch_bounds__(256, 2)
void attn_flash(const ushort_t* __restrict__ qh, const ushort_t* __restrict__ kh,
                const ushort_t* __restrict__ vt, const ushort_t* __restrict__ qrel,
                ushort_t* __restrict__ Ptile, float* __restrict__ w1g,
                float* __restrict__ lacg, float* __restrict__ b0g,
                float* __restrict__ b256g)
{
    __shared__ ushort_t Ks[64 * 64];
    __shared__ ushort_t Vs[64 * 64];
    __shared__ ushort_t PQs[128 * 64];   // Q at start, then P (kappa cols)
    char* Ksb = (char*)Ks; char* Vsb = (char*)Vs; char* PQb = (char*)PQs;

    const int t = threadIdx.x, lane = t & 63, w = t >> 6;
    const int g = lane >> 4, c16 = lane & 15;
    int flat = blockIdx.y * gridDim.x + blockIdx.x;          // nwg = 512
    int rmid = (flat & 7) * 64 + (flat >> 3);
    const int q0 = (rmid & 15) * 128;
    const int bh = rmid >> 4;
    const size_t Gbase = (size_t)rmid * 6;

    // stage Q[128][64] -> LDS (swizzled) -> register fragments
#pragma unroll
    for (int l = 0; l < 4; ++l) {
        const int fid = t + 256 * l;                         // 0..1023
        const int row = fid >> 3, ch = fid & 7;
        uint4 v = *reinterpret_cast<const uint4*>(
            qh + ((size_t)bh * SQ + q0 + row) * DH + ch * 8);
        *reinterpret_cast<uint4*>(PQb + lswz(row, ch * 16)) = v;
    }
    __syncthreads();
    bf16x8 qf[2][2];
#pragma unroll
    for (int st = 0; st < 2; ++st)
#pragma unroll
        for (int ks = 0; ks < 2; ++ks)
            qf[st][ks] = *reinterpret_cast<const bf16x8*>(
                PQb + lswz(w * 16 + st * 64 + c16, ks * 64 + g * 16));

    float q0add[2][4], q256add[2][4];
#pragma unroll
    for (int st = 0; st < 2; ++st)
#pragma unroll
        for (int i = 0; i < 4; ++i) {
            const size_t r = (size_t)bh * SQ + q0 + w * 16 + st * 64 + 4 * g + i;
            q0add[st][i]   = bf2f(qrel[r * QSTR + 0]);
            q256add[st][i] = bf2f(qrel[r * QSTR + 256]);
        }

    f32x4 w1[2][4];
#pragma unroll
    for (int st = 0; st < 2; ++st)
#pragma unroll
        for (int n = 0; n < 4; ++n) w1[st][n] = (f32x4){0.f, 0.f, 0.f, 0.f};
    float lac[2][4] = {}, b0[2][4] = {}, b256[2][4] = {};

    // pipelined K/V staging registers
    const int row_l = t >> 3, ch_l = t & 7;
    const int row_h = row_l + 32;
    uint4 kr0, kr1, vr0, vr1;
    kr0 = *reinterpret_cast<const uint4*>(kh + ((size_t)bh * SQ + row_l) * DH + ch_l * 8);
    kr1 = *reinterpret_cast<const uint4*>(kh + ((size_t)bh * SQ + row_h) * DH + ch_l * 8);
    vr0 = *reinterpret_cast<const uint4*>(vt + ((size_t)bh * DH + row_l) * SQ + ch_l * 8);
    vr1 = *reinterpret_cast<const uint4*>(vt + ((size_t)bh * DH + row_h) * SQ + ch_l * 8);

    for (int k0 = 0; k0 < SQ; k0 += 64) {
        __syncthreads();   // prev tile's MFMA LDS reads done (also covers qf loads)
        *reinterpret_cast<uint4*>(Ksb + lswz(row_l, ch_l * 16)) = kr0;
        *reinterpret_cast<uint4*>(Ksb + lswz(row_h, ch_l * 16)) = kr1;
        *reinterpret_cast<uint4*>(Vsb + lswz(row_l, ch_l * 16)) = vr0;
        *reinterpret_cast<uint4*>(Vsb + lswz(row_h, ch_l * 16)) = vr1;
        __syncthreads();
        if (k0 + 64 < SQ) {   // prefetch next tile; latency hidden by compute
            kr0 = *reinterpret_cast<const uint4*>(kh + ((size_t)bh * SQ + k0 + 64 + row_l) * DH + ch_l * 8);
            kr1 = *reinterpret_cast<const uint4*>(kh + ((size_t)bh * SQ + k0 + 64 + row_h) * DH + ch_l * 8);
            vr0 = *reinterpret_cast<const uint4*>(vt + ((size_t)bh * DH + row_l) * SQ + k0 + 64 + ch_l * 8);
            vr1 = *reinterpret_cast<const uint4*>(vt + ((size_t)bh * DH + row_h) * SQ + k0 + 64 + ch_l * 8);
        }

        // S = Q K^T : kf frags shared across both q-strips
        f32x4 s[2][4];
#pragma unroll
        for (int st = 0; st < 2; ++st)
#pragma unroll
            for (int n = 0; n < 4; ++n) s[st][n] = (f32x4){0.f, 0.f, 0.f, 0.f};
        {
            bf16x8 kf[4][2];
#pragma unroll
            for (int n = 0; n < 4; ++n)
#pragma unroll
                for (int ks = 0; ks < 2; ++ks)
                    kf[n][ks] = *reinterpret_cast<const bf16x8*>(
                        Ksb + lswz(16 * n + c16, ks * 64 + g * 16));
            __builtin_amdgcn_s_setprio(1);
#pragma unroll
            for (int st = 0; st < 2; ++st)
#pragma unroll
                for (int ks = 0; ks < 2; ++ks)
#pragma unroll
                    for (int n = 0; n < 4; ++n)
                        s[st][n] = MFMA16(qf[st][ks], kf[n][ks], s[st][n]);
            __builtin_amdgcn_s_setprio(0);
        }

        const int rel0 = k0 - q0;
        if (rel0 <= -192 || rel0 >= 256) {                 // far: uniform bias
            const bool lo = rel0 < 0;
#pragma unroll
            for (int st = 0; st < 2; ++st)
#pragma unroll
                for (int i = 0; i < 4; ++i) {
                    const float add = lo ? q0add[st][i] : q256add[st][i];
                    float rs = 0.f;
#pragma unroll
                    for (int n = 0; n < 4; ++n) {
                        const float p = exp2f(fmaf(s[st][n][i], SCL, add));
                        s[st][n][i] = p; rs += p;
                    }
                    lac[st][i] += rs;
                    if (lo) b0[st][i] += rs; else b256[st][i] += rs;
                    const int qloc = w * 16 + st * 64 + 4 * g + i;
                    *reinterpret_cast<uint2*>(PQb + lswz(qloc, c16 * 8)) =
                        pack4(s[st][0][i], s[st][1][i], s[st][2][i], s[st][3][i]);
                }
        } else {                                           // band tile (6 per block)
            const int tix = (rel0 + 128) >> 6;
            const bool mixed = (rel0 < 0) | (rel0 > 64);
#pragma unroll
            for (int st = 0; st < 2; ++st)
#pragma unroll
                for (int i = 0; i < 4; ++i) {
                    const int qloc = w * 16 + st * 64 + 4 * g + i;
                    const int qg = q0 + qloc;
                    const ushort_t* qrow = qrel + ((size_t)bh * SQ + qg) * QSTR;
                    float z[4];
                    float rs = 0.f;
#pragma unroll
                    for (int n = 0; n < 4; ++n) {
                        const int rel = rel0 + 16 * n + c16 - qloc;
                        int idx;
                        if (mixed) idx = rel < -128 ? 0 : (rel > 128 ? 256 : rel + 128);
                        else       idx = rel + 128;
                        const float p = exp2f(fmaf(s[st][n][i], SCL, bf2f(qrow[idx])));
                        s[st][n][i] = p; rs += p;
                        if (mixed) {
                            const bool inb = (rel >= -127) & (rel <= 127);
                            z[n] = inb ? p : 0.f;
                            if (rel <= -128)      b0[st][i] += p;
                            else if (rel >= 128)  b256[st][i] += p;
                        } else z[n] = p;
                    }
                    lac[st][i] += rs;
                    *reinterpret_cast<uint2*>(PQb + lswz(qloc, c16 * 8)) =
                        pack4(s[st][0][i], s[st][1][i], s[st][2][i], s[st][3][i]);
                    *reinterpret_cast<uint2*>(
                        Ptile + ((Gbase + tix) * 128 + qloc) * 64 + 4 * c16) =
                        pack4(z[0], z[1], z[2], z[3]);
                }
        }

        // w1 += P @ V : vf frags shared across both q-strips
        {
            bf16x8 vf[4][2];
#pragma unroll
            for (int n = 0; n < 4; ++n)
#pragma unroll
                for (int ks = 0; ks < 2; ++ks)
                    vf[n][ks] = *reinterpret_cast<const bf16x8*>(
                        Vsb + lswz(16 * n + c16, ks * 64 + g * 16));
            bf16x8 pf[2][2];
#pragma unroll
            for (int st = 0; st < 2; ++st)
#pragma unroll
                for (int ks = 0; ks < 2; ++ks)
                    pf[st][ks] = *reinterpret_cast<const bf16x8*>(
                        PQb + lswz(w * 16 + st * 64 + c16, ks * 64 + g * 16));
            __builtin_amdgcn_s_setprio(1);
#pragma unroll
            for (int st = 0; st < 2; ++st)
#pragma unroll
                for (int ks = 0; ks < 2; ++ks)
#pragma unroll
                    for (int n = 0; n < 4; ++n)
                        w1[st][n] = MFMA16(pf[st][ks], vf[n][ks], w1[st][n]);
            __builtin_amdgcn_s_setprio(0);
        }
    }

#pragma unroll
    for (int m = 1; m < 16; m <<= 1)
#pragma unroll
        for (int st = 0; st < 2; ++st)
#pragma unroll
            for (int i = 0; i < 4; ++i) {
                lac[st][i]  += __shfl_xor(lac[st][i],  m, 64);
                b0[st][i]   += __shfl_xor(b0[st][i],   m, 64);
                b256[st][i] += __shfl_xor(b256[st][i], m, 64);
            }
    if (c16 == 0) {
#pragma unroll
        for (int st = 0; st < 2; ++st)
#pragma unroll
            for (int i = 0; i < 4; ++i) {
                const size_t row = (size_t)bh * SQ + q0 + w * 16 + st * 64 + 4 * g + i;
                lacg[row] = lac[st][i]; b0g[row] = b0[st][i]; b256g[row] = b256[st][i];
            }
    }
#pragma unroll
    for (int st = 0; st < 2; ++st)
#pragma unroll
        for (int n = 0; n < 4; ++n)
#pragma unroll
            for (int i = 0; i < 4; ++i) {
                const size_t row = (size_t)bh * SQ + q0 + w * 16 + st * 64 + 4 * g + i;
                w1g[row * DH + 16 * n + c16] = w1[st][n][i];
            }
}

// ---------------------------------------------------------------------------
// Band GEMM + combine: scatter 6 P tiles into shifted LDS layout
// Pband[q][kperm(rel+127)] (bucket 255 = b256 mass), w2 = Pband @ rvT^T,
// out = (w1 + w2 + b0*rv[0]) / lac  -> wbuf [B,S,H,D] bf16.
// ---------------------------------------------------------------------------
__global__ __launch_bounds__(256)
void band_gemm(const ushort_t* __restrict__ Ptile, const ushort_t* __restrict__ rvT,
               const float* __restrict__ rv_f32, const float* __restrict__ w1g,
               const float* __restrict__ lacg, const float* __restrict__ b0g,
               const float* __restrict__ b256g, ushort_t* __restrict__ wout)
{
    __shared__ ushort_t Pband[64 * 264];
    const int t = threadIdx.x, lane = t & 63, w = t >> 6;
    const int g = lane >> 4, c16 = lane & 15;
    const int blk = blockIdx.x;           // 0..1023 (64-row groups)
    const size_t r0 = (size_t)blk * 64;
    const int G = blk >> 1;               // q-block-128 id = bh*16 + qb
    const int half = blk & 1;
    const int q0 = (G & 15) * 128;

    for (int i = t; i < 64 * 264 / 2; i += 256)
        reinterpret_cast<unsigned*>(Pband)[i] = 0u;
    __syncthreads();

    // scatter tiles (coalesced reads, LDS b16 scatter)
    for (int u = t; u < 6 * 64 * 16; u += 256) {
        const int tix = u >> 10;                       // 0..5
        const int kt0 = q0 + tix * 64 - 128;
        if (kt0 < 0 || kt0 >= SQ) continue;
        const int qloc64 = (u >> 4) & 63;
        const int c = u & 15;
        const int qloc128 = half * 64 + qloc64;
        uint2 pv = *reinterpret_cast<const uint2*>(
            Ptile + (((size_t)G * 6 + tix) * 128 + qloc128) * 64 + 4 * c);
        const ushort_t* pe = reinterpret_cast<const ushort_t*>(&pv);
        const int relbase = tix * 64 - 1 - qloc128;    // x = relbase + 16n + c
#pragma unroll
        for (int n = 0; n < 4; ++n) {
            const int x = relbase + 16 * n + c;
            if (x >= 0 && x <= 254)
                Pband[qloc64 * 264 + ((x & ~63) | ((x & 15) << 2) | ((x >> 4) & 3))] = pe[n];
        }
    }
    if (t < 64) Pband[t * 264 + 255] = f2bf(b256g[r0 + t]);
    __syncthreads();

    f32x4 acc[4];
#pragma unroll
    for (int n = 0; n < 4; ++n) acc[n] = (f32x4){0.f, 0.f, 0.f, 0.f};
#pragma unroll
    for (int ks = 0; ks < 8; ++ks) {
        bf16x8 pm = *reinterpret_cast<const bf16x8*>(
            Pband + (w * 16 + c16) * 264 + ks * 32 + g * 8);
#pragma unroll
        for (int n = 0; n < 4; ++n) {
            bf16x8 rf = *reinterpret_cast<const bf16x8*>(
                rvT + (size_t)(16 * n + c16) * 256 + ks * 32 + g * 8);
            acc[n] = MFMA16(pm, rf, acc[n]);
        }
    }

#pragma unroll
    for (int i = 0; i < 4; ++i) {
        const size_t row = r0 + w * 16 + 4 * g + i;
        const float inv = 1.0f / lacg[row];
        const float vb0 = b0g[row];
        const int b = (int)(row >> 15), h = (int)((row >> 11) & 15), s = (int)(row & 2047);
#pragma unroll
        for (int n = 0; n < 4; ++n) {
            const int col = 16 * n + c16;
            const float val = (w1g[row * DH + col] + acc[n][i] + vb0 * rv_f32[col]) * inv;
            wout[(((size_t)b * SQ + s) * NH + h) * DH + col] = f2bf(val);
        }
    }
}

// ---------------------------------------------------------------------------
extern "C" void kernel_launch(void* const* d_in, const int* in_sizes, int n_in,
                              void* d_out, int out_size, void* d_ws, size_t ws_size,
                              hipStream_t stream)
{
    const float* q  = (const float*)d_in[0];
    const float* k  = (const float*)d_in[1];
    const float* v  = (const float*)d_in[2];
    const float* Wq = (const float*)d_in[3];
    const float* bq = (const float*)d_in[4];
    const float* Wk = (const float*)d_in[5];
    const float* bk = (const float*)d_in[6];
    const float* Wv = (const float*)d_in[7];
    const float* bv = (const float*)d_in[8];
    const float* Wo = (const float*)d_in[9];
    const float* bo = (const float*)d_in[10];
    const float* rk = (const float*)d_in[11];
    const float* rv = (const float*)d_in[12];

    char* ws = (char*)d_ws;
    auto alloc = [&](size_t bytes) { char* p = ws; ws += bytes; return p; };
    const size_t QB = (size_t)NB * SQ * EM * 2;       // 8 MB
    const size_t NR = (size_t)NB * NH * SQ;           // 65536 rows

    ushort_t* Ptile = (ushort_t*)alloc((size_t)512 * 6 * 128 * 64 * 2);  // 50.3 MB
    ushort_t* qhb  = (ushort_t*)alloc(QB);            // [B,H,S,D]
    ushort_t* khb  = (ushort_t*)alloc(QB);            // [B,H,S,D]
    ushort_t* vtb  = (ushort_t*)alloc(QB);            // [B,H,D,S'] kappa-permuted
    ushort_t* rvT  = (ushort_t*)alloc(64 * 256 * 2);
    ushort_t* rkb  = (ushort_t*)alloc(272 * 64 * 2);
    char*     qrel_region = alloc(NR * QSTR * 2);     // 33.8 MB
    ushort_t* qrel = (ushort_t*)qrel_region;          // dead after attn_flash
    ushort_t* wbuf = (ushort_t*)qrel_region;          // alias: written by band_gemm
    float*    w1g  = (float*)alloc(NR * DH * 4);
    float*    lacg = (float*)alloc(NR * 4);
    float*    b0g  = (float*)alloc(NR * 4);
    float*    b256g= (float*)alloc(NR * 4);

    prep_tables<<<132, 256, 0, stream>>>(rv, rk, rvT, rkb);

    const int M = NB * SQ;
    dim3 gg(EM / 128, M / 128);
    gemm_bt<1, 1><<<gg, 256, 0, stream>>>(q, Wq, bq, qhb, M, EM, EM);
    gemm_bt<1, 1><<<gg, 256, 0, stream>>>(k, Wk, bk, khb, M, EM, EM);
    gemm_bt<2, 1><<<gg, 256, 0, stream>>>(v, Wv, bv, vtb, M, EM, EM);
    qrel_mfma<<<(int)(NR / 64), 256, 0, stream>>>(qhb, rkb, qrel);

    attn_flash<<<dim3(16, 32), 256, 0, stream>>>(qhb, khb, vtb, qrel,
                                                 Ptile, w1g, lacg, b0g, b256g);
    band_gemm<<<(int)(NR / 64), 256, 0, stream>>>(Ptile, rvT, rv, w1g, lacg,
                                                  b0g, b256g, wbuf);
    gemm_bt<0, 0><<<gg, 256, 0, stream>>>(wbuf, Wo, bo, d_out, M, EM, EM);
}